// Round 22
// baseline (269.809 us; speedup 1.0000x reference)
//
#include <hip/hip_runtime.h>
#include <math.h>

// CapsNet dynamic routing, all-MFMA (16x16x32), hi/lo split packed into K.
//   x: [512,1152,8] f32, w: [10,1152,16,8] f32, out: [512,10,16] f32
// p0: w -> bf16 hi/lo natural [c][n][d][k].
// p1: register-landing mfma(K = 4n x 8k), NS1=36, lb(256,4)  (R16 exact).
// p2 (R22): LDS-staged w (R16 staging, single buffer, 2 barriers/stage) but each
//     block processes TWO b-tiles against the same staged tile (grid y 32->16):
//     staging traffic and barrier drains amortized 2x. Tiles sequential per stage;
//     only acc0[10]+acc1[10] (80 VGPR) persist -> peak live ~125, no spill expected.
// Partials -> P[ns][b][160]; reduce_squash sums + squashes.

#define BB   512
#define NN1  1152
#define CD   160
#define XB   (NN1*8)           // 9216
#define WELEM (10*NN1*16*8)    // 1474560

typedef __attribute__((ext_vector_type(8))) short bf16x8;
typedef __attribute__((ext_vector_type(4))) float f32x4;

#define MFMA32(a, b, c) __builtin_amdgcn_mfma_f32_16x16x32_bf16(a, b, c, 0, 0, 0)
#define ZERO4 ((f32x4){0.f, 0.f, 0.f, 0.f})

__device__ __forceinline__ short f2bf(float f) {
    unsigned u = __builtin_bit_cast(unsigned, f);
    u += 0x7FFFu + ((u >> 16) & 1u);
    return (short)(u >> 16);
}
__device__ __forceinline__ float bf2f(short s) {
    unsigned u = ((unsigned)(unsigned short)s) << 16;
    return __builtin_bit_cast(float, u);
}
__device__ __forceinline__ void cvt_hilo8(f32x4 a, f32x4 b, bf16x8& h, bf16x8& l) {
#pragma unroll
    for (int i = 0; i < 4; ++i) {
        short t = f2bf(a[i]); h[i] = t; l[i] = f2bf(a[i] - bf2f(t));
        t = f2bf(b[i]); h[4 + i] = t; l[4 + i] = f2bf(b[i] - bf2f(t));
    }
}
__device__ __forceinline__ int opaque_zero() {
    int z;
    asm volatile("v_mov_b32 %0, 0" : "=v"(z));
    return z;
}
__device__ __forceinline__ void load_lds16(const short* gp, char* lp) {
    __builtin_amdgcn_global_load_lds(
        (const __attribute__((address_space(1))) void*)gp,
        (__attribute__((address_space(3))) void*)lp, 16, 0, 0);
}
// stage 8 n's of w hi/lo into a 40KB buffer (hi segs c*2+q at 0, lo at 20480)
__device__ __forceinline__ void stage8(const short* wnh, const short* wnl,
                                       char* buf, int n0, int wv, int lane)
{
    const short* gsrc = (wv < 2) ? wnh : wnl;
    char* ldst = buf + ((wv < 2) ? 0 : 20480);
    const int segbase = (wv & 1) * 10;
#pragma unroll
    for (int j = 0; j < 10; ++j) {
        const int s = segbase + j;
        const short* gp = gsrc + ((size_t)((s >> 1) * NN1 + n0 + (s & 1) * 4)) * 128 + lane * 8;
        load_lds16(gp, ldst + s * 1024);
    }
}

// ---------------- p0: w -> wnat hi/lo ----------------
__global__ void p0(const float* __restrict__ w,
                   short* __restrict__ wnh, short* __restrict__ wnl)
{
    int i = blockIdx.x * 256 + threadIdx.x;      // 5760*256 == WELEM
    float f = w[i];
    short h = f2bf(f);
    wnh[i] = h;
    wnl[i] = f2bf(f - bf2f(h));
}

// ---------------- p1: s0 partials, mfma over (4n x 8k)  (R16 exact) ----------------
template<int NS>
__global__ __launch_bounds__(256, 4) void caps_p1(
    const float* __restrict__ x, const short* __restrict__ wnh, const short* __restrict__ wnl,
    float* __restrict__ P)
{
    constexpr int NT = NN1 / NS;
    constexpr int QPW = NT / 16;
    static_assert(NT % 16 == 0, "balanced quads");
    __shared__ float red[2][2560];

    const int ns = blockIdx.x, bt = blockIdx.y;
    const int tid = threadIdx.x, lane = tid & 63, wv = tid >> 6;
    const int lo = lane & 15, g = lane >> 4;
    const int btile = bt * 16;

    f32x4 acc[10];
#pragma unroll
    for (int c = 0; c < 10; ++c) acc[c] = ZERO4;

#pragma unroll 2
    for (int it = 0; it < QPW; ++it) {
        const int n0 = ns * NT + (wv * QPW + it) * 4;
        const float* px = x + (size_t)(btile + lo) * XB + (size_t)(n0 + g) * 8;
        f32x4 x0 = *(const f32x4*)px;
        f32x4 x1 = *(const f32x4*)(px + 4);
        bf16x8 ah, al;
        cvt_hilo8(x0, x1, ah, al);
#pragma unroll
        for (int c = 0; c < 10; ++c) {
            size_t off = (((size_t)c * NN1 + n0 + g) * 16 + lo) * 8;
            bf16x8 bh = *(const bf16x8*)(wnh + off);
            bf16x8 bl = *(const bf16x8*)(wnl + off);
            acc[c] = MFMA32(ah, bh, acc[c]);
            acc[c] = MFMA32(al, bh, acc[c]);
            acc[c] = MFMA32(ah, bl, acc[c]);
        }
    }

    if (wv == 1 || wv == 3) {
        float* s = red[wv >> 1];
#pragma unroll
        for (int c = 0; c < 10; ++c)
#pragma unroll
            for (int e = 0; e < 4; ++e) s[c * 256 + (g * 4 + e) * 16 + lo] = acc[c][e];
    }
    __syncthreads();
    if (wv == 0) {
#pragma unroll
        for (int c = 0; c < 10; ++c)
#pragma unroll
            for (int e = 0; e < 4; ++e) acc[c][e] += red[0][c * 256 + (g * 4 + e) * 16 + lo];
    } else if (wv == 2) {
#pragma unroll
        for (int c = 0; c < 10; ++c)
#pragma unroll
            for (int e = 0; e < 4; ++e) {
                int idx = c * 256 + (g * 4 + e) * 16 + lo;
                red[1][idx] += acc[c][e];
            }
    }
    __syncthreads();
    if (wv == 0) {
        float* dst = P + (size_t)ns * BB * CD;
#pragma unroll
        for (int c = 0; c < 10; ++c)
#pragma unroll
            for (int e = 0; e < 4; ++e)
                dst[(size_t)(btile + g * 4 + e) * CD + c * 16 + lo] =
                    acc[c][e] + red[1][c * 256 + (g * 4 + e) * 16 + lo];
    }
}

// ------- reduce over ns + squash(alpha*S) -------
__global__ void reduce_squash(const float* __restrict__ P, float* __restrict__ out,
                              int nsplit, float asq)
{
    int t = blockIdx.x * 256 + threadIdx.x;      // 320*256 == 81920
    float s = 0.f;
    const float* p = P + t;
    for (int ns = 0; ns < nsplit; ++ns, p += (size_t)BB * CD) s += *p;
    float sq = s * s;
#pragma unroll
    for (int m = 1; m < 16; m <<= 1) sq += __shfl_xor(sq, m, 64);
    float qq = asq * sq;
    float sc = qq / (1.f + qq) / sqrtf(sq);
    out[t] = s * sc;
}

// per-(b-tile, stage) body: x load -> pass1 logits -> softmax -> pass2 accumulate
__device__ __forceinline__ void p2_tile(
    const float* __restrict__ x, const char* lds, int ap_base, int opq,
    const float* po0, int b, int na, int g, f32x4* acc, bf16x8 z8)
{
    const float* px = x + (size_t)b * XB + (size_t)na * 8;
    f32x4 x0a = *(const f32x4*)px,       x0b = *(const f32x4*)(px + 4);
    f32x4 x1a = *(const f32x4*)(px + 8), x1b = *(const f32x4*)(px + 12);

    bf16x8 xh0, xl0, xh1, xl1;
    cvt_hilo8(x0a, x0b, xh0, xl0);
    cvt_hilo8(x1a, x1b, xh1, xl1);

    bf16x8 Bx0, Bx1;                             // [x_hi | x_hi | x_lo | 0] along K
    if (g == 3)      { Bx0 = z8;  Bx1 = z8;  }
    else if (g == 2) { Bx0 = xl0; Bx1 = xl1; }
    else             { Bx0 = xh0; Bx1 = xh1; }

    // pass 1: y from LDS A-frags -> logit dot -> shfl d-reduce
    float L0[10], L1[10];
#pragma unroll
    for (int c = 0; c < 10; ++c) {
        bf16x8 A0 = *(const bf16x8*)(lds + ap_base + c * 2048);
        bf16x8 A1 = *(const bf16x8*)(lds + ap_base + c * 2048 + 256);
        f32x4 y0 = MFMA32(A0, Bx0, ZERO4);
        f32x4 y1 = MFMA32(A1, Bx1, ZERO4);
        f32x4 ov = *(const f32x4*)(po0 + c * 16);
        float lp0 = y0[0]*ov[0] + y0[1]*ov[1] + y0[2]*ov[2] + y0[3]*ov[3];
        float lp1 = y1[0]*ov[0] + y1[1]*ov[1] + y1[2]*ov[2] + y1[3]*ov[3];
        lp0 += __shfl_xor(lp0, 16, 64);
        lp0 += __shfl_xor(lp0, 32, 64);
        lp1 += __shfl_xor(lp1, 16, 64);
        lp1 += __shfl_xor(lp1, 32, 64);
        L0[c] = lp0;
        L1[c] = lp1;
    }
    // softmax in-lane; raw exp (|L| < ~0.3)
    float d0 = 0.f, d1 = 0.f;
#pragma unroll
    for (int c = 0; c < 10; ++c) {
        L0[c] = __expf(L0[c]); d0 += L0[c];
        L1[c] = __expf(L1[c]); d1 += L1[c];
    }
    float i0 = 1.f / d0, i1 = 1.f / d1;
    // pass 2: re-read LDS (laundered addr -> no CSE), acc += c1 * y
#pragma unroll
    for (int c = 0; c < 10; ++c) {
        bf16x8 A0 = *(const bf16x8*)(lds + opq + ap_base + c * 2048);
        bf16x8 A1 = *(const bf16x8*)(lds + opq + ap_base + c * 2048 + 256);
        f32x4 y0 = MFMA32(A0, Bx0, ZERO4);
        f32x4 y1 = MFMA32(A1, Bx1, ZERO4);
        float c0f = L0[c] * i0, c1f = L1[c] * i1;
#pragma unroll
        for (int e = 0; e < 4; ++e) acc[c][e] += c0f * y0[e] + c1f * y1[e];
    }
}

// ---------------- p2: LDS-staged w shared by TWO b-tiles per block ----------------
template<int NS>
__global__ __launch_bounds__(256, 2) void caps_p2(
    const float* __restrict__ x,
    const short* __restrict__ wnh, const short* __restrict__ wnl,
    const float* __restrict__ o0, float* __restrict__ P)
{
    constexpr int NT = NN1 / NS;
    constexpr int ITER = NT / 8;
    static_assert(NT % 8 == 0, "8n per stage");

    __shared__ __align__(16) char lds[40960];    // hi at 0, lo at 20480; reused for reduce

    const int ns = blockIdx.x, bt = blockIdx.y;  // bt in [0,16): b-tile PAIR
    const int tid = threadIdx.x, lane = tid & 63, wv = tid >> 6;
    const int lo = lane & 15, g = lane >> 4;
    const int btile0 = bt * 32, btile1 = bt * 32 + 16;
    const int b0 = btile0 + lo, b1 = btile1 + lo;

    const int ap_base = ((g == 1) ? 20480 : 0) + wv * 512 + lo * 16;   // n_loc = wv*2
    const int opq = opaque_zero();
    const float* po0a = o0 + (size_t)b0 * CD + g * 4;
    const float* po0b = o0 + (size_t)b1 * CD + g * 4;

    f32x4 acc0[10], acc1[10];
#pragma unroll
    for (int c = 0; c < 10; ++c) { acc0[c] = ZERO4; acc1[c] = ZERO4; }

    const bf16x8 z8 = {0, 0, 0, 0, 0, 0, 0, 0};

    for (int it = 0; it < ITER; ++it) {
        const int n0 = ns * NT + it * 8;

        __syncthreads();
        stage8(wnh, wnl, lds, n0, wv, lane);
        __syncthreads();

        const int na = n0 + wv * 2;
        p2_tile(x, lds, ap_base, opq, po0a, b0, na, g, acc0, z8);
        p2_tile(x, lds, ap_base, opq, po0b, b1, na, g, acc1, z8);
    }

    // 4-wave reduce for each tile, reusing lds
    float* red0 = (float*)lds;
    float* red1 = (float*)(lds + 10240);
#pragma unroll
    for (int t = 0; t < 2; ++t) {
        f32x4* acc = t ? acc1 : acc0;
        const int btile = t ? btile1 : btile0;
        __syncthreads();   // WAR vs staged-w reads (t=0) / previous reduce reads (t=1)
        if (wv == 1 || wv == 3) {
            float* s = (wv == 1) ? red0 : red1;
#pragma unroll
            for (int c = 0; c < 10; ++c)
#pragma unroll
                for (int e = 0; e < 4; ++e) s[c * 256 + (g * 4 + e) * 16 + lo] = acc[c][e];
        }
        __syncthreads();
        if (wv == 0) {
#pragma unroll
            for (int c = 0; c < 10; ++c)
#pragma unroll
                for (int e = 0; e < 4; ++e) acc[c][e] += red0[c * 256 + (g * 4 + e) * 16 + lo];
        } else if (wv == 2) {
#pragma unroll
            for (int c = 0; c < 10; ++c)
#pragma unroll
                for (int e = 0; e < 4; ++e) {
                    int idx = c * 256 + (g * 4 + e) * 16 + lo;
                    red1[idx] += acc[c][e];
                }
        }
        __syncthreads();
        if (wv == 0) {
            float* dst = P + (size_t)ns * BB * CD;
#pragma unroll
            for (int c = 0; c < 10; ++c)
#pragma unroll
                for (int e = 0; e < 4; ++e)
                    dst[(size_t)(btile + lo) * CD + c * 16 + g * 4 + e] =
                        acc[c][e] + red1[c * 256 + (g * 4 + e) * 16 + lo];
        }
    }
}

extern "C" void kernel_launch(void* const* d_in, const int* in_sizes, int n_in,
                              void* d_out, int out_size, void* d_ws, size_t ws_size,
                              hipStream_t stream)
{
    (void)in_sizes; (void)n_in; (void)out_size;
    const float* x = (const float*)d_in[0];
    const float* w = (const float*)d_in[1];
    float* out = (float*)d_out;

    char* base = (char*)d_ws;
    short* wnh = (short*)(base);
    short* wnl = (short*)(base + 2949120);
    float* o0  = (float*)(base + 5898240);
    float* P   = (float*)(base + 6225920);
    const size_t fixed = 6225920, slab = (size_t)BB * CD * sizeof(float);

    p0<<<WELEM / 256, 256, 0, stream>>>(w, wnh, wnl);

#define LAUNCH_NS(NS1, NS2)                                                            \
    do {                                                                               \
        caps_p1<NS1><<<dim3(NS1, 32), 256, 0, stream>>>(x, wnh, wnl, P);               \
        reduce_squash<<<320, 256, 0, stream>>>(P, o0, NS1, 0.01f);                     \
        caps_p2<NS2><<<dim3(NS2, 16), 256, 0, stream>>>(x, wnh, wnl, o0, P);           \
        reduce_squash<<<320, 256, 0, stream>>>(P, out, NS2, 1.0f);                     \
    } while (0)

    if      (ws_size >= fixed + slab * 36) LAUNCH_NS(36, 36);   // NT=32, 4 stages each
    else if (ws_size >= fixed + slab * 12) LAUNCH_NS(12, 12);
    else                                   LAUNCH_NS(4, 4);
#undef LAUNCH_NS
}

// Round 23
// 95.333 us; speedup vs baseline: 2.8302x; 2.8302x over previous
//
#include <hip/hip_runtime.h>
#include <math.h>

// CapsNet dynamic routing, all-MFMA (16x16x32), hi/lo split packed into K.
//   x: [512,1152,8] f32, w: [10,1152,16,8] f32, out: [512,10,16] f32
// p0: w -> bf16 hi/lo natural [c][n][d][k].
// p1: register-landing mfma(K = 4n x 8k), NS1=36, lb(256,4)  (R16 exact).
// p2 (R23): R16 body, but 16 n's staged per stage as two 40KB halves (LDS 80KB,
//     still 2 blocks/CU) -> barrier pairs halve. Inner loop = R16 per-n-pair body
//     run twice with #pragma unroll 1 (NOT interleaved -> live set stays ~84 regs;
//     R22's two-acc interleave spilled 422MB).
// Partials -> P[ns][b][160]; reduce_squash sums + squashes.

#define BB   512
#define NN1  1152
#define CD   160
#define XB   (NN1*8)           // 9216
#define WELEM (10*NN1*16*8)    // 1474560

typedef __attribute__((ext_vector_type(8))) short bf16x8;
typedef __attribute__((ext_vector_type(4))) float f32x4;

#define MFMA32(a, b, c) __builtin_amdgcn_mfma_f32_16x16x32_bf16(a, b, c, 0, 0, 0)
#define ZERO4 ((f32x4){0.f, 0.f, 0.f, 0.f})

__device__ __forceinline__ short f2bf(float f) {
    unsigned u = __builtin_bit_cast(unsigned, f);
    u += 0x7FFFu + ((u >> 16) & 1u);
    return (short)(u >> 16);
}
__device__ __forceinline__ float bf2f(short s) {
    unsigned u = ((unsigned)(unsigned short)s) << 16;
    return __builtin_bit_cast(float, u);
}
__device__ __forceinline__ void cvt_hilo8(f32x4 a, f32x4 b, bf16x8& h, bf16x8& l) {
#pragma unroll
    for (int i = 0; i < 4; ++i) {
        short t = f2bf(a[i]); h[i] = t; l[i] = f2bf(a[i] - bf2f(t));
        t = f2bf(b[i]); h[4 + i] = t; l[4 + i] = f2bf(b[i] - bf2f(t));
    }
}
__device__ __forceinline__ int opaque_zero() {
    int z;
    asm volatile("v_mov_b32 %0, 0" : "=v"(z));
    return z;
}
__device__ __forceinline__ void load_lds16(const short* gp, char* lp) {
    __builtin_amdgcn_global_load_lds(
        (const __attribute__((address_space(1))) void*)gp,
        (__attribute__((address_space(3))) void*)lp, 16, 0, 0);
}
// stage 8 n's of w hi/lo: hi -> dstbase, lo -> dstbase + loOff (segments c*2+q, 1KB)
__device__ __forceinline__ void stage8o(const short* wnh, const short* wnl,
                                        char* dstbase, int loOff, int n0, int wv, int lane)
{
    const short* gsrc = (wv < 2) ? wnh : wnl;
    char* ldst = dstbase + ((wv < 2) ? 0 : loOff);
    const int segbase = (wv & 1) * 10;
#pragma unroll
    for (int j = 0; j < 10; ++j) {
        const int s = segbase + j;
        const short* gp = gsrc + ((size_t)((s >> 1) * NN1 + n0 + (s & 1) * 4)) * 128 + lane * 8;
        load_lds16(gp, ldst + s * 1024);
    }
}

// ---------------- p0: w -> wnat hi/lo ----------------
__global__ void p0(const float* __restrict__ w,
                   short* __restrict__ wnh, short* __restrict__ wnl)
{
    int i = blockIdx.x * 256 + threadIdx.x;      // 5760*256 == WELEM
    float f = w[i];
    short h = f2bf(f);
    wnh[i] = h;
    wnl[i] = f2bf(f - bf2f(h));
}

// ---------------- p1: s0 partials, mfma over (4n x 8k)  (R16 exact) ----------------
template<int NS>
__global__ __launch_bounds__(256, 4) void caps_p1(
    const float* __restrict__ x, const short* __restrict__ wnh, const short* __restrict__ wnl,
    float* __restrict__ P)
{
    constexpr int NT = NN1 / NS;
    constexpr int QPW = NT / 16;
    static_assert(NT % 16 == 0, "balanced quads");
    __shared__ float red[2][2560];

    const int ns = blockIdx.x, bt = blockIdx.y;
    const int tid = threadIdx.x, lane = tid & 63, wv = tid >> 6;
    const int lo = lane & 15, g = lane >> 4;
    const int btile = bt * 16;

    f32x4 acc[10];
#pragma unroll
    for (int c = 0; c < 10; ++c) acc[c] = ZERO4;

#pragma unroll 2
    for (int it = 0; it < QPW; ++it) {
        const int n0 = ns * NT + (wv * QPW + it) * 4;
        const float* px = x + (size_t)(btile + lo) * XB + (size_t)(n0 + g) * 8;
        f32x4 x0 = *(const f32x4*)px;
        f32x4 x1 = *(const f32x4*)(px + 4);
        bf16x8 ah, al;
        cvt_hilo8(x0, x1, ah, al);
#pragma unroll
        for (int c = 0; c < 10; ++c) {
            size_t off = (((size_t)c * NN1 + n0 + g) * 16 + lo) * 8;
            bf16x8 bh = *(const bf16x8*)(wnh + off);
            bf16x8 bl = *(const bf16x8*)(wnl + off);
            acc[c] = MFMA32(ah, bh, acc[c]);
            acc[c] = MFMA32(al, bh, acc[c]);
            acc[c] = MFMA32(ah, bl, acc[c]);
        }
    }

    if (wv == 1 || wv == 3) {
        float* s = red[wv >> 1];
#pragma unroll
        for (int c = 0; c < 10; ++c)
#pragma unroll
            for (int e = 0; e < 4; ++e) s[c * 256 + (g * 4 + e) * 16 + lo] = acc[c][e];
    }
    __syncthreads();
    if (wv == 0) {
#pragma unroll
        for (int c = 0; c < 10; ++c)
#pragma unroll
            for (int e = 0; e < 4; ++e) acc[c][e] += red[0][c * 256 + (g * 4 + e) * 16 + lo];
    } else if (wv == 2) {
#pragma unroll
        for (int c = 0; c < 10; ++c)
#pragma unroll
            for (int e = 0; e < 4; ++e) {
                int idx = c * 256 + (g * 4 + e) * 16 + lo;
                red[1][idx] += acc[c][e];
            }
    }
    __syncthreads();
    if (wv == 0) {
        float* dst = P + (size_t)ns * BB * CD;
#pragma unroll
        for (int c = 0; c < 10; ++c)
#pragma unroll
            for (int e = 0; e < 4; ++e)
                dst[(size_t)(btile + g * 4 + e) * CD + c * 16 + lo] =
                    acc[c][e] + red[1][c * 256 + (g * 4 + e) * 16 + lo];
    }
}

// ------- reduce over ns + squash(alpha*S) -------
__global__ void reduce_squash(const float* __restrict__ P, float* __restrict__ out,
                              int nsplit, float asq)
{
    int t = blockIdx.x * 256 + threadIdx.x;      // 320*256 == 81920
    float s = 0.f;
    const float* p = P + t;
    for (int ns = 0; ns < nsplit; ++ns, p += (size_t)BB * CD) s += *p;
    float sq = s * s;
#pragma unroll
    for (int m = 1; m < 16; m <<= 1) sq += __shfl_xor(sq, m, 64);
    float qq = asq * sq;
    float sc = qq / (1.f + qq) / sqrtf(sq);
    out[t] = s * sc;
}

// ---------------- p2: 16-n staged (two 40KB halves), R16 per-pair body ----------------
template<int NS>
__global__ __launch_bounds__(256, 2) void caps_p2(
    const float* __restrict__ x,
    const short* __restrict__ wnh, const short* __restrict__ wnl,
    const float* __restrict__ o0, float* __restrict__ P)
{
    constexpr int NT = NN1 / NS;
    constexpr int ITER = NT / 16;    // 16 n's staged per iteration
    static_assert(NT % 16 == 0, "16n per stage");

    __shared__ __align__(16) char lds[81920];    // hi: [0,40960) in 2 halves; lo: +40960

    const int ns = blockIdx.x, bt = blockIdx.y;
    const int tid = threadIdx.x, lane = tid & 63, wv = tid >> 6;
    const int lo = lane & 15, g = lane >> 4;
    const int btile = bt * 16;
    const int b = btile + lo;

    const int opq = opaque_zero();
    const float* po0 = o0 + (size_t)b * CD + g * 4;

    f32x4 acc[10];
#pragma unroll
    for (int c = 0; c < 10; ++c) acc[c] = ZERO4;

    const bf16x8 z8 = {0, 0, 0, 0, 0, 0, 0, 0};

    for (int it = 0; it < ITER; ++it) {
        const int n0 = ns * NT + it * 16;

        __syncthreads();   // WAR on previous stage
        stage8o(wnh, wnl, lds,         40960, n0,     wv, lane);   // half 0: n0..n0+7
        stage8o(wnh, wnl, lds + 20480, 40960, n0 + 8, wv, lane);   // half 1: n0+8..n0+15
        __syncthreads();   // staging complete (barrier drains vmcnt)

#pragma unroll 1
        for (int h2 = 0; h2 < 2; ++h2) {         // two n-pairs sequentially (NOT interleaved)
            const int ap_base = ((g == 1) ? 40960 : 0) + h2 * 20480 + wv * 512 + lo * 16;
            const int na = n0 + h2 * 8 + wv * 2;
            const float* px = x + (size_t)b * XB + (size_t)na * 8;
            f32x4 x0a = *(const f32x4*)px,       x0b = *(const f32x4*)(px + 4);
            f32x4 x1a = *(const f32x4*)(px + 8), x1b = *(const f32x4*)(px + 12);

            bf16x8 xh0, xl0, xh1, xl1;
            cvt_hilo8(x0a, x0b, xh0, xl0);
            cvt_hilo8(x1a, x1b, xh1, xl1);

            bf16x8 Bx0, Bx1;                     // [x_hi | x_hi | x_lo | 0] along K
            if (g == 3)      { Bx0 = z8;  Bx1 = z8;  }
            else if (g == 2) { Bx0 = xl0; Bx1 = xl1; }
            else             { Bx0 = xh0; Bx1 = xh1; }

            // ---- pass 1: y from LDS A-frags -> logit dot -> shfl d-reduce ----
            float L0[10], L1[10];
#pragma unroll
            for (int c = 0; c < 10; ++c) {
                bf16x8 A0 = *(const bf16x8*)(lds + ap_base + c * 2048);
                bf16x8 A1 = *(const bf16x8*)(lds + ap_base + c * 2048 + 256);
                f32x4 y0 = MFMA32(A0, Bx0, ZERO4);
                f32x4 y1 = MFMA32(A1, Bx1, ZERO4);
                f32x4 ov = *(const f32x4*)(po0 + c * 16);
                float lp0 = y0[0]*ov[0] + y0[1]*ov[1] + y0[2]*ov[2] + y0[3]*ov[3];
                float lp1 = y1[0]*ov[0] + y1[1]*ov[1] + y1[2]*ov[2] + y1[3]*ov[3];
                lp0 += __shfl_xor(lp0, 16, 64);
                lp0 += __shfl_xor(lp0, 32, 64);
                lp1 += __shfl_xor(lp1, 16, 64);
                lp1 += __shfl_xor(lp1, 32, 64);
                L0[c] = lp0;
                L1[c] = lp1;
            }

            // ---- softmax in-lane; raw exp (|L| < ~0.3) ----
            float d0 = 0.f, d1 = 0.f;
#pragma unroll
            for (int c = 0; c < 10; ++c) {
                L0[c] = __expf(L0[c]); d0 += L0[c];
                L1[c] = __expf(L1[c]); d1 += L1[c];
            }
            float i0 = 1.f / d0, i1 = 1.f / d1;

            // ---- pass 2: re-read LDS (laundered addr -> no CSE), acc += c1 * y ----
#pragma unroll
            for (int c = 0; c < 10; ++c) {
                bf16x8 A0 = *(const bf16x8*)(lds + opq + ap_base + c * 2048);
                bf16x8 A1 = *(const bf16x8*)(lds + opq + ap_base + c * 2048 + 256);
                f32x4 y0 = MFMA32(A0, Bx0, ZERO4);
                f32x4 y1 = MFMA32(A1, Bx1, ZERO4);
                float c0f = L0[c] * i0, c1f = L1[c] * i1;
#pragma unroll
                for (int e = 0; e < 4; ++e) acc[c][e] += c0f * y0[e] + c1f * y1[e];
            }
        }
    }

    // 4-wave reduce, reusing lds
    __syncthreads();
    float* red0 = (float*)lds;
    float* red1 = (float*)(lds + 10240);
    if (wv == 1 || wv == 3) {
        float* s = (wv == 1) ? red0 : red1;
#pragma unroll
        for (int c = 0; c < 10; ++c)
#pragma unroll
            for (int e = 0; e < 4; ++e) s[c * 256 + (g * 4 + e) * 16 + lo] = acc[c][e];
    }
    __syncthreads();
    if (wv == 0) {
#pragma unroll
        for (int c = 0; c < 10; ++c)
#pragma unroll
            for (int e = 0; e < 4; ++e) acc[c][e] += red0[c * 256 + (g * 4 + e) * 16 + lo];
    } else if (wv == 2) {
#pragma unroll
        for (int c = 0; c < 10; ++c)
#pragma unroll
            for (int e = 0; e < 4; ++e) {
                int idx = c * 256 + (g * 4 + e) * 16 + lo;
                red1[idx] += acc[c][e];
            }
    }
    __syncthreads();
    if (wv == 0) {
        float* dst = P + (size_t)ns * BB * CD;
#pragma unroll
        for (int c = 0; c < 10; ++c)
#pragma unroll
            for (int e = 0; e < 4; ++e)
                dst[(size_t)(btile + lo) * CD + c * 16 + g * 4 + e] =
                    acc[c][e] + red1[c * 256 + (g * 4 + e) * 16 + lo];
    }
}

extern "C" void kernel_launch(void* const* d_in, const int* in_sizes, int n_in,
                              void* d_out, int out_size, void* d_ws, size_t ws_size,
                              hipStream_t stream)
{
    (void)in_sizes; (void)n_in; (void)out_size;
    const float* x = (const float*)d_in[0];
    const float* w = (const float*)d_in[1];
    float* out = (float*)d_out;

    char* base = (char*)d_ws;
    short* wnh = (short*)(base);
    short* wnl = (short*)(base + 2949120);
    float* o0  = (float*)(base + 5898240);
    float* P   = (float*)(base + 6225920);
    const size_t fixed = 6225920, slab = (size_t)BB * CD * sizeof(float);

    p0<<<WELEM / 256, 256, 0, stream>>>(w, wnh, wnl);

#define LAUNCH_NS(NS1, NS2)                                                            \
    do {                                                                               \
        caps_p1<NS1><<<dim3(NS1, 32), 256, 0, stream>>>(x, wnh, wnl, P);               \
        reduce_squash<<<320, 256, 0, stream>>>(P, o0, NS1, 0.01f);                     \
        caps_p2<NS2><<<dim3(NS2, 32), 256, 0, stream>>>(x, wnh, wnl, o0, P);           \
        reduce_squash<<<320, 256, 0, stream>>>(P, out, NS2, 1.0f);                     \
    } while (0)

    if      (ws_size >= fixed + slab * 36) LAUNCH_NS(36, 36);   // p2: NT=32, 2 stages
    else if (ws_size >= fixed + slab * 12) LAUNCH_NS(12, 12);
    else                                   LAUNCH_NS(4, 4);
#undef LAUNCH_NS
}

// Round 24
// 85.859 us; speedup vs baseline: 3.1425x; 1.1103x over previous
//
#include <hip/hip_runtime.h>
#include <math.h>

// CapsNet dynamic routing, all-MFMA (16x16x32), hi/lo split packed into K.
//   x: [512,1152,8] f32, w: [10,1152,16,8] f32, out: [512,10,16] f32
// R24 = R21 structure (measured best: 87.8us) + TRUNCATION hi/lo split:
//   hi = trunc-bf16(f) (1 op), lo = trunc-bf16(f - hi) — split is exact regardless of
//   hi's rounding mode, so the RNE bit-trick (~7 VALU/value) is wasted work. ~40% of
//   p2's per-pair VALU removed; same for p1/p0. Error 2^-17 -> 2^-16 (absmax ~1e-3).
// p1: register-landing mfma(K = 4n x 8k), NS1=36, lb(256,4).
// p2: LDS-staged w via global_load_lds, single buffer, 2 barriers/stage, lb(256,2),
//     two-pass y recompute. (All other levers measured dead: R17/R18/R20/R22/R23.)
// Partials -> P[ns][b][160]; reduce_squash sums + squashes.

#define BB   512
#define NN1  1152
#define CD   160
#define XB   (NN1*8)           // 9216
#define WELEM (10*NN1*16*8)    // 1474560

typedef __attribute__((ext_vector_type(8))) short bf16x8;
typedef __attribute__((ext_vector_type(4))) float f32x4;

#define MFMA32(a, b, c) __builtin_amdgcn_mfma_f32_16x16x32_bf16(a, b, c, 0, 0, 0)
#define ZERO4 ((f32x4){0.f, 0.f, 0.f, 0.f})

// truncation-split helpers (R24): hi = f's top 16 bits; lo = trunc-bf16(f - hi)
__device__ __forceinline__ void cvt_hilo8(f32x4 a, f32x4 b, bf16x8& h, bf16x8& l) {
#pragma unroll
    for (int i = 0; i < 4; ++i) {
        unsigned ua = __builtin_bit_cast(unsigned, a[i]);
        float hfa = __builtin_bit_cast(float, ua & 0xFFFF0000u);
        h[i] = (short)(ua >> 16);
        l[i] = (short)(__builtin_bit_cast(unsigned, a[i] - hfa) >> 16);
        unsigned ub = __builtin_bit_cast(unsigned, b[i]);
        float hfb = __builtin_bit_cast(float, ub & 0xFFFF0000u);
        h[4 + i] = (short)(ub >> 16);
        l[4 + i] = (short)(__builtin_bit_cast(unsigned, b[i] - hfb) >> 16);
    }
}
__device__ __forceinline__ int opaque_zero() {
    int z;
    asm volatile("v_mov_b32 %0, 0" : "=v"(z));
    return z;
}
__device__ __forceinline__ void load_lds16(const short* gp, char* lp) {
    __builtin_amdgcn_global_load_lds(
        (const __attribute__((address_space(1))) void*)gp,
        (__attribute__((address_space(3))) void*)lp, 16, 0, 0);
}
// stage 8 n's of w hi/lo into a 40KB buffer (hi segs c*2+q at 0, lo at 20480)
__device__ __forceinline__ void stage8(const short* wnh, const short* wnl,
                                       char* buf, int n0, int wv, int lane)
{
    const short* gsrc = (wv < 2) ? wnh : wnl;
    char* ldst = buf + ((wv < 2) ? 0 : 20480);
    const int segbase = (wv & 1) * 10;
#pragma unroll
    for (int j = 0; j < 10; ++j) {
        const int s = segbase + j;
        const short* gp = gsrc + ((size_t)((s >> 1) * NN1 + n0 + (s & 1) * 4)) * 128 + lane * 8;
        load_lds16(gp, ldst + s * 1024);
    }
}

// ---------------- p0: w -> wnat hi/lo (truncation split) ----------------
__global__ void p0(const float* __restrict__ w,
                   short* __restrict__ wnh, short* __restrict__ wnl)
{
    int i = blockIdx.x * 256 + threadIdx.x;      // 5760*256 == WELEM
    float f = w[i];
    unsigned u = __builtin_bit_cast(unsigned, f);
    float hf = __builtin_bit_cast(float, u & 0xFFFF0000u);
    wnh[i] = (short)(u >> 16);
    wnl[i] = (short)(__builtin_bit_cast(unsigned, f - hf) >> 16);
}

// ---------------- p1: s0 partials, mfma over (4n x 8k) ----------------
template<int NS>
__global__ __launch_bounds__(256, 4) void caps_p1(
    const float* __restrict__ x, const short* __restrict__ wnh, const short* __restrict__ wnl,
    float* __restrict__ P)
{
    constexpr int NT = NN1 / NS;
    constexpr int QPW = NT / 16;
    static_assert(NT % 16 == 0, "balanced quads");
    __shared__ float red[2][2560];

    const int ns = blockIdx.x, bt = blockIdx.y;
    const int tid = threadIdx.x, lane = tid & 63, wv = tid >> 6;
    const int lo = lane & 15, g = lane >> 4;
    const int btile = bt * 16;

    f32x4 acc[10];
#pragma unroll
    for (int c = 0; c < 10; ++c) acc[c] = ZERO4;

#pragma unroll 2
    for (int it = 0; it < QPW; ++it) {
        const int n0 = ns * NT + (wv * QPW + it) * 4;
        const float* px = x + (size_t)(btile + lo) * XB + (size_t)(n0 + g) * 8;
        f32x4 x0 = *(const f32x4*)px;
        f32x4 x1 = *(const f32x4*)(px + 4);
        bf16x8 ah, al;
        cvt_hilo8(x0, x1, ah, al);
#pragma unroll
        for (int c = 0; c < 10; ++c) {
            size_t off = (((size_t)c * NN1 + n0 + g) * 16 + lo) * 8;
            bf16x8 bh = *(const bf16x8*)(wnh + off);
            bf16x8 bl = *(const bf16x8*)(wnl + off);
            acc[c] = MFMA32(ah, bh, acc[c]);
            acc[c] = MFMA32(al, bh, acc[c]);
            acc[c] = MFMA32(ah, bl, acc[c]);
        }
    }

    if (wv == 1 || wv == 3) {
        float* s = red[wv >> 1];
#pragma unroll
        for (int c = 0; c < 10; ++c)
#pragma unroll
            for (int e = 0; e < 4; ++e) s[c * 256 + (g * 4 + e) * 16 + lo] = acc[c][e];
    }
    __syncthreads();
    if (wv == 0) {
#pragma unroll
        for (int c = 0; c < 10; ++c)
#pragma unroll
            for (int e = 0; e < 4; ++e) acc[c][e] += red[0][c * 256 + (g * 4 + e) * 16 + lo];
    } else if (wv == 2) {
#pragma unroll
        for (int c = 0; c < 10; ++c)
#pragma unroll
            for (int e = 0; e < 4; ++e) {
                int idx = c * 256 + (g * 4 + e) * 16 + lo;
                red[1][idx] += acc[c][e];
            }
    }
    __syncthreads();
    if (wv == 0) {
        float* dst = P + (size_t)ns * BB * CD;
#pragma unroll
        for (int c = 0; c < 10; ++c)
#pragma unroll
            for (int e = 0; e < 4; ++e)
                dst[(size_t)(btile + g * 4 + e) * CD + c * 16 + lo] =
                    acc[c][e] + red[1][c * 256 + (g * 4 + e) * 16 + lo];
    }
}

// ------- reduce over ns + squash(alpha*S) -------
__global__ void reduce_squash(const float* __restrict__ P, float* __restrict__ out,
                              int nsplit, float asq)
{
    int t = blockIdx.x * 256 + threadIdx.x;      // 320*256 == 81920
    float s = 0.f;
    const float* p = P + t;
    for (int ns = 0; ns < nsplit; ++ns, p += (size_t)BB * CD) s += *p;
    float sq = s * s;
#pragma unroll
    for (int m = 1; m < 16; m <<= 1) sq += __shfl_xor(sq, m, 64);
    float qq = asq * sq;
    float sc = qq / (1.f + qq) / sqrtf(sq);
    out[t] = s * sc;
}

// ---------------- p2: LDS-staged w, two-pass y, in-lane softmax ----------------
template<int NS>
__global__ __launch_bounds__(256, 2) void caps_p2(
    const float* __restrict__ x,
    const short* __restrict__ wnh, const short* __restrict__ wnl,
    const float* __restrict__ o0, float* __restrict__ P)
{
    constexpr int NT = NN1 / NS;
    constexpr int ITER = NT / 8;     // 8 n's staged per iteration
    static_assert(NT % 8 == 0, "8n per stage");

    __shared__ __align__(16) char lds[40960];    // hi at 0, lo at 20480; reused for reduce

    const int ns = blockIdx.x, bt = blockIdx.y;
    const int tid = threadIdx.x, lane = tid & 63, wv = tid >> 6;
    const int lo = lane & 15, g = lane >> 4;
    const int btile = bt * 16;
    const int b = btile + lo;

    const int ap_base = ((g == 1) ? 20480 : 0) + wv * 512 + lo * 16;   // n_loc = wv*2
    const int opq = opaque_zero();
    const float* po0 = o0 + (size_t)b * CD + g * 4;

    f32x4 acc[10];
#pragma unroll
    for (int c = 0; c < 10; ++c) acc[c] = ZERO4;

    const bf16x8 z8 = {0, 0, 0, 0, 0, 0, 0, 0};

    for (int it = 0; it < ITER; ++it) {
        const int n0 = ns * NT + it * 8;

        __syncthreads();
        stage8(wnh, wnl, lds, n0, wv, lane);
        __syncthreads();

        const int na = n0 + wv * 2;
        const float* px = x + (size_t)b * XB + (size_t)na * 8;
        f32x4 x0a = *(const f32x4*)px,       x0b = *(const f32x4*)(px + 4);
        f32x4 x1a = *(const f32x4*)(px + 8), x1b = *(const f32x4*)(px + 12);

        bf16x8 xh0, xl0, xh1, xl1;
        cvt_hilo8(x0a, x0b, xh0, xl0);
        cvt_hilo8(x1a, x1b, xh1, xl1);

        bf16x8 Bx0, Bx1;                         // [x_hi | x_hi | x_lo | 0] along K
        if (g == 3)      { Bx0 = z8;  Bx1 = z8;  }
        else if (g == 2) { Bx0 = xl0; Bx1 = xl1; }
        else             { Bx0 = xh0; Bx1 = xh1; }

        // ---- pass 1: y from LDS A-frags -> logit dot -> shfl d-reduce ----
        float L0[10], L1[10];
#pragma unroll
        for (int c = 0; c < 10; ++c) {
            bf16x8 A0 = *(const bf16x8*)(lds + ap_base + c * 2048);
            bf16x8 A1 = *(const bf16x8*)(lds + ap_base + c * 2048 + 256);
            f32x4 y0 = MFMA32(A0, Bx0, ZERO4);
            f32x4 y1 = MFMA32(A1, Bx1, ZERO4);
            f32x4 ov = *(const f32x4*)(po0 + c * 16);
            float lp0 = y0[0]*ov[0] + y0[1]*ov[1] + y0[2]*ov[2] + y0[3]*ov[3];
            float lp1 = y1[0]*ov[0] + y1[1]*ov[1] + y1[2]*ov[2] + y1[3]*ov[3];
            lp0 += __shfl_xor(lp0, 16, 64);
            lp0 += __shfl_xor(lp0, 32, 64);
            lp1 += __shfl_xor(lp1, 16, 64);
            lp1 += __shfl_xor(lp1, 32, 64);
            L0[c] = lp0;
            L1[c] = lp1;
        }

        // ---- softmax in-lane; raw exp (|L| < ~0.3) ----
        float d0 = 0.f, d1 = 0.f;
#pragma unroll
        for (int c = 0; c < 10; ++c) {
            L0[c] = __expf(L0[c]); d0 += L0[c];
            L1[c] = __expf(L1[c]); d1 += L1[c];
        }
        float i0 = 1.f / d0, i1 = 1.f / d1;

        // ---- pass 2: re-read LDS (laundered addr -> no CSE), acc += c1 * y ----
#pragma unroll
        for (int c = 0; c < 10; ++c) {
            bf16x8 A0 = *(const bf16x8*)(lds + opq + ap_base + c * 2048);
            bf16x8 A1 = *(const bf16x8*)(lds + opq + ap_base + c * 2048 + 256);
            f32x4 y0 = MFMA32(A0, Bx0, ZERO4);
            f32x4 y1 = MFMA32(A1, Bx1, ZERO4);
            float c0f = L0[c] * i0, c1f = L1[c] * i1;
#pragma unroll
            for (int e = 0; e < 4; ++e) acc[c][e] += c0f * y0[e] + c1f * y1[e];
        }
    }

    // 4-wave reduce, reusing lds
    __syncthreads();
    float* red0 = (float*)lds;
    float* red1 = (float*)(lds + 10240);
    if (wv == 1 || wv == 3) {
        float* s = (wv == 1) ? red0 : red1;
#pragma unroll
        for (int c = 0; c < 10; ++c)
#pragma unroll
            for (int e = 0; e < 4; ++e) s[c * 256 + (g * 4 + e) * 16 + lo] = acc[c][e];
    }
    __syncthreads();
    if (wv == 0) {
#pragma unroll
        for (int c = 0; c < 10; ++c)
#pragma unroll
            for (int e = 0; e < 4; ++e) acc[c][e] += red0[c * 256 + (g * 4 + e) * 16 + lo];
    } else if (wv == 2) {
#pragma unroll
        for (int c = 0; c < 10; ++c)
#pragma unroll
            for (int e = 0; e < 4; ++e) {
                int idx = c * 256 + (g * 4 + e) * 16 + lo;
                red1[idx] += acc[c][e];
            }
    }
    __syncthreads();
    if (wv == 0) {
        float* dst = P + (size_t)ns * BB * CD;
#pragma unroll
        for (int c = 0; c < 10; ++c)
#pragma unroll
            for (int e = 0; e < 4; ++e)
                dst[(size_t)(btile + lo) * CD + c * 16 + g * 4 + e] =
                    acc[c][e] + red1[c * 256 + (g * 4 + e) * 16 + lo];
    }
}

extern "C" void kernel_launch(void* const* d_in, const int* in_sizes, int n_in,
                              void* d_out, int out_size, void* d_ws, size_t ws_size,
                              hipStream_t stream)
{
    (void)in_sizes; (void)n_in; (void)out_size;
    const float* x = (const float*)d_in[0];
    const float* w = (const float*)d_in[1];
    float* out = (float*)d_out;

    char* base = (char*)d_ws;
    short* wnh = (short*)(base);
    short* wnl = (short*)(base + 2949120);
    float* o0  = (float*)(base + 5898240);
    float* P   = (float*)(base + 6225920);
    const size_t fixed = 6225920, slab = (size_t)BB * CD * sizeof(float);

    p0<<<WELEM / 256, 256, 0, stream>>>(w, wnh, wnl);

#define LAUNCH_NS(NS1, NS2)                                                            \
    do {                                                                               \
        caps_p1<NS1><<<dim3(NS1, 32), 256, 0, stream>>>(x, wnh, wnl, P);               \
        reduce_squash<<<320, 256, 0, stream>>>(P, o0, NS1, 0.01f);                     \
        caps_p2<NS2><<<dim3(NS2, 32), 256, 0, stream>>>(x, wnh, wnl, o0, P);           \
        reduce_squash<<<320, 256, 0, stream>>>(P, out, NS2, 1.0f);                     \
    } while (0)

    if      (ws_size >= fixed + slab * 36) LAUNCH_NS(36, 36);   // NT=32, 4 stages each
    else if (ws_size >= fixed + slab * 12) LAUNCH_NS(12, 12);
    else                                   LAUNCH_NS(4, 4);
#undef LAUNCH_NS
}

// Round 25
// 75.626 us; speedup vs baseline: 3.5677x; 1.1353x over previous
//
#include <hip/hip_runtime.h>
#include <math.h>

// CapsNet dynamic routing, all-MFMA (16x16x32), hi/lo split packed into K.
//   x: [512,1152,8] f32, w: [10,1152,16,8] f32, out: [512,10,16] f32
// R25 = R24 bodies exact + grid/wave-quantization fix:
//   p2: NS2=16 (NT=72, 9 stages) -> 512 blocks == 2/CU slots exactly, 1 round
//       (was 1152 blocks on 512 slots = 3 rounds, 25% idle tail).
//   p1: NS1=24 (NT=48) + lb(256,3) -> 768 blocks == 3/CU slots exactly, 1 round
//       (was 1152 on 1024 = 2 rounds); 85-reg bucket removes 64-reg squeeze risk.
// p0/reduce unchanged; truncation hi/lo split (R24); two-pass y p2 (R16/R21).
// Partials -> P[ns][b][160]; reduce_squash sums + squashes.

#define BB   512
#define NN1  1152
#define CD   160
#define XB   (NN1*8)           // 9216
#define WELEM (10*NN1*16*8)    // 1474560

typedef __attribute__((ext_vector_type(8))) short bf16x8;
typedef __attribute__((ext_vector_type(4))) float f32x4;

#define MFMA32(a, b, c) __builtin_amdgcn_mfma_f32_16x16x32_bf16(a, b, c, 0, 0, 0)
#define ZERO4 ((f32x4){0.f, 0.f, 0.f, 0.f})

// truncation-split helpers (R24): hi = f's top 16 bits; lo = trunc-bf16(f - hi)
__device__ __forceinline__ void cvt_hilo8(f32x4 a, f32x4 b, bf16x8& h, bf16x8& l) {
#pragma unroll
    for (int i = 0; i < 4; ++i) {
        unsigned ua = __builtin_bit_cast(unsigned, a[i]);
        float hfa = __builtin_bit_cast(float, ua & 0xFFFF0000u);
        h[i] = (short)(ua >> 16);
        l[i] = (short)(__builtin_bit_cast(unsigned, a[i] - hfa) >> 16);
        unsigned ub = __builtin_bit_cast(unsigned, b[i]);
        float hfb = __builtin_bit_cast(float, ub & 0xFFFF0000u);
        h[4 + i] = (short)(ub >> 16);
        l[4 + i] = (short)(__builtin_bit_cast(unsigned, b[i] - hfb) >> 16);
    }
}
__device__ __forceinline__ int opaque_zero() {
    int z;
    asm volatile("v_mov_b32 %0, 0" : "=v"(z));
    return z;
}
__device__ __forceinline__ void load_lds16(const short* gp, char* lp) {
    __builtin_amdgcn_global_load_lds(
        (const __attribute__((address_space(1))) void*)gp,
        (__attribute__((address_space(3))) void*)lp, 16, 0, 0);
}
// stage 8 n's of w hi/lo into a 40KB buffer (hi segs c*2+q at 0, lo at 20480)
__device__ __forceinline__ void stage8(const short* wnh, const short* wnl,
                                       char* buf, int n0, int wv, int lane)
{
    const short* gsrc = (wv < 2) ? wnh : wnl;
    char* ldst = buf + ((wv < 2) ? 0 : 20480);
    const int segbase = (wv & 1) * 10;
#pragma unroll
    for (int j = 0; j < 10; ++j) {
        const int s = segbase + j;
        const short* gp = gsrc + ((size_t)((s >> 1) * NN1 + n0 + (s & 1) * 4)) * 128 + lane * 8;
        load_lds16(gp, ldst + s * 1024);
    }
}

// ---------------- p0: w -> wnat hi/lo (truncation split) ----------------
__global__ void p0(const float* __restrict__ w,
                   short* __restrict__ wnh, short* __restrict__ wnl)
{
    int i = blockIdx.x * 256 + threadIdx.x;      // 5760*256 == WELEM
    float f = w[i];
    unsigned u = __builtin_bit_cast(unsigned, f);
    float hf = __builtin_bit_cast(float, u & 0xFFFF0000u);
    wnh[i] = (short)(u >> 16);
    wnl[i] = (short)(__builtin_bit_cast(unsigned, f - hf) >> 16);
}

// ---------------- p1: s0 partials, mfma over (4n x 8k) ----------------
template<int NS>
__global__ __launch_bounds__(256, 3) void caps_p1(
    const float* __restrict__ x, const short* __restrict__ wnh, const short* __restrict__ wnl,
    float* __restrict__ P)
{
    constexpr int NT = NN1 / NS;
    constexpr int QPW = NT / 16;
    static_assert(NT % 16 == 0, "balanced quads");
    __shared__ float red[2][2560];

    const int ns = blockIdx.x, bt = blockIdx.y;
    const int tid = threadIdx.x, lane = tid & 63, wv = tid >> 6;
    const int lo = lane & 15, g = lane >> 4;
    const int btile = bt * 16;

    f32x4 acc[10];
#pragma unroll
    for (int c = 0; c < 10; ++c) acc[c] = ZERO4;

#pragma unroll 2
    for (int it = 0; it < QPW; ++it) {
        const int n0 = ns * NT + (wv * QPW + it) * 4;
        const float* px = x + (size_t)(btile + lo) * XB + (size_t)(n0 + g) * 8;
        f32x4 x0 = *(const f32x4*)px;
        f32x4 x1 = *(const f32x4*)(px + 4);
        bf16x8 ah, al;
        cvt_hilo8(x0, x1, ah, al);
#pragma unroll
        for (int c = 0; c < 10; ++c) {
            size_t off = (((size_t)c * NN1 + n0 + g) * 16 + lo) * 8;
            bf16x8 bh = *(const bf16x8*)(wnh + off);
            bf16x8 bl = *(const bf16x8*)(wnl + off);
            acc[c] = MFMA32(ah, bh, acc[c]);
            acc[c] = MFMA32(al, bh, acc[c]);
            acc[c] = MFMA32(ah, bl, acc[c]);
        }
    }

    if (wv == 1 || wv == 3) {
        float* s = red[wv >> 1];
#pragma unroll
        for (int c = 0; c < 10; ++c)
#pragma unroll
            for (int e = 0; e < 4; ++e) s[c * 256 + (g * 4 + e) * 16 + lo] = acc[c][e];
    }
    __syncthreads();
    if (wv == 0) {
#pragma unroll
        for (int c = 0; c < 10; ++c)
#pragma unroll
            for (int e = 0; e < 4; ++e) acc[c][e] += red[0][c * 256 + (g * 4 + e) * 16 + lo];
    } else if (wv == 2) {
#pragma unroll
        for (int c = 0; c < 10; ++c)
#pragma unroll
            for (int e = 0; e < 4; ++e) {
                int idx = c * 256 + (g * 4 + e) * 16 + lo;
                red[1][idx] += acc[c][e];
            }
    }
    __syncthreads();
    if (wv == 0) {
        float* dst = P + (size_t)ns * BB * CD;
#pragma unroll
        for (int c = 0; c < 10; ++c)
#pragma unroll
            for (int e = 0; e < 4; ++e)
                dst[(size_t)(btile + g * 4 + e) * CD + c * 16 + lo] =
                    acc[c][e] + red[1][c * 256 + (g * 4 + e) * 16 + lo];
    }
}

// ------- reduce over ns + squash(alpha*S) -------
__global__ void reduce_squash(const float* __restrict__ P, float* __restrict__ out,
                              int nsplit, float asq)
{
    int t = blockIdx.x * 256 + threadIdx.x;      // 320*256 == 81920
    float s = 0.f;
    const float* p = P + t;
    for (int ns = 0; ns < nsplit; ++ns, p += (size_t)BB * CD) s += *p;
    float sq = s * s;
#pragma unroll
    for (int m = 1; m < 16; m <<= 1) sq += __shfl_xor(sq, m, 64);
    float qq = asq * sq;
    float sc = qq / (1.f + qq) / sqrtf(sq);
    out[t] = s * sc;
}

// ---------------- p2: LDS-staged w, two-pass y, in-lane softmax ----------------
template<int NS>
__global__ __launch_bounds__(256, 2) void caps_p2(
    const float* __restrict__ x,
    const short* __restrict__ wnh, const short* __restrict__ wnl,
    const float* __restrict__ o0, float* __restrict__ P)
{
    constexpr int NT = NN1 / NS;
    constexpr int ITER = NT / 8;     // 8 n's staged per iteration
    static_assert(NT % 8 == 0, "8n per stage");

    __shared__ __align__(16) char lds[40960];    // hi at 0, lo at 20480; reused for reduce

    const int ns = blockIdx.x, bt = blockIdx.y;
    const int tid = threadIdx.x, lane = tid & 63, wv = tid >> 6;
    const int lo = lane & 15, g = lane >> 4;
    const int btile = bt * 16;
    const int b = btile + lo;

    const int ap_base = ((g == 1) ? 20480 : 0) + wv * 512 + lo * 16;   // n_loc = wv*2
    const int opq = opaque_zero();
    const float* po0 = o0 + (size_t)b * CD + g * 4;

    f32x4 acc[10];
#pragma unroll
    for (int c = 0; c < 10; ++c) acc[c] = ZERO4;

    const bf16x8 z8 = {0, 0, 0, 0, 0, 0, 0, 0};

    for (int it = 0; it < ITER; ++it) {
        const int n0 = ns * NT + it * 8;

        __syncthreads();
        stage8(wnh, wnl, lds, n0, wv, lane);
        __syncthreads();

        const int na = n0 + wv * 2;
        const float* px = x + (size_t)b * XB + (size_t)na * 8;
        f32x4 x0a = *(const f32x4*)px,       x0b = *(const f32x4*)(px + 4);
        f32x4 x1a = *(const f32x4*)(px + 8), x1b = *(const f32x4*)(px + 12);

        bf16x8 xh0, xl0, xh1, xl1;
        cvt_hilo8(x0a, x0b, xh0, xl0);
        cvt_hilo8(x1a, x1b, xh1, xl1);

        bf16x8 Bx0, Bx1;                         // [x_hi | x_hi | x_lo | 0] along K
        if (g == 3)      { Bx0 = z8;  Bx1 = z8;  }
        else if (g == 2) { Bx0 = xl0; Bx1 = xl1; }
        else             { Bx0 = xh0; Bx1 = xh1; }

        // ---- pass 1: y from LDS A-frags -> logit dot -> shfl d-reduce ----
        float L0[10], L1[10];
#pragma unroll
        for (int c = 0; c < 10; ++c) {
            bf16x8 A0 = *(const bf16x8*)(lds + ap_base + c * 2048);
            bf16x8 A1 = *(const bf16x8*)(lds + ap_base + c * 2048 + 256);
            f32x4 y0 = MFMA32(A0, Bx0, ZERO4);
            f32x4 y1 = MFMA32(A1, Bx1, ZERO4);
            f32x4 ov = *(const f32x4*)(po0 + c * 16);
            float lp0 = y0[0]*ov[0] + y0[1]*ov[1] + y0[2]*ov[2] + y0[3]*ov[3];
            float lp1 = y1[0]*ov[0] + y1[1]*ov[1] + y1[2]*ov[2] + y1[3]*ov[3];
            lp0 += __shfl_xor(lp0, 16, 64);
            lp0 += __shfl_xor(lp0, 32, 64);
            lp1 += __shfl_xor(lp1, 16, 64);
            lp1 += __shfl_xor(lp1, 32, 64);
            L0[c] = lp0;
            L1[c] = lp1;
        }

        // ---- softmax in-lane; raw exp (|L| < ~0.3) ----
        float d0 = 0.f, d1 = 0.f;
#pragma unroll
        for (int c = 0; c < 10; ++c) {
            L0[c] = __expf(L0[c]); d0 += L0[c];
            L1[c] = __expf(L1[c]); d1 += L1[c];
        }
        float i0 = 1.f / d0, i1 = 1.f / d1;

        // ---- pass 2: re-read LDS (laundered addr -> no CSE), acc += c1 * y ----
#pragma unroll
        for (int c = 0; c < 10; ++c) {
            bf16x8 A0 = *(const bf16x8*)(lds + opq + ap_base + c * 2048);
            bf16x8 A1 = *(const bf16x8*)(lds + opq + ap_base + c * 2048 + 256);
            f32x4 y0 = MFMA32(A0, Bx0, ZERO4);
            f32x4 y1 = MFMA32(A1, Bx1, ZERO4);
            float c0f = L0[c] * i0, c1f = L1[c] * i1;
#pragma unroll
            for (int e = 0; e < 4; ++e) acc[c][e] += c0f * y0[e] + c1f * y1[e];
        }
    }

    // 4-wave reduce, reusing lds
    __syncthreads();
    float* red0 = (float*)lds;
    float* red1 = (float*)(lds + 10240);
    if (wv == 1 || wv == 3) {
        float* s = (wv == 1) ? red0 : red1;
#pragma unroll
        for (int c = 0; c < 10; ++c)
#pragma unroll
            for (int e = 0; e < 4; ++e) s[c * 256 + (g * 4 + e) * 16 + lo] = acc[c][e];
    }
    __syncthreads();
    if (wv == 0) {
#pragma unroll
        for (int c = 0; c < 10; ++c)
#pragma unroll
            for (int e = 0; e < 4; ++e) acc[c][e] += red0[c * 256 + (g * 4 + e) * 16 + lo];
    } else if (wv == 2) {
#pragma unroll
        for (int c = 0; c < 10; ++c)
#pragma unroll
            for (int e = 0; e < 4; ++e) {
                int idx = c * 256 + (g * 4 + e) * 16 + lo;
                red1[idx] += acc[c][e];
            }
    }
    __syncthreads();
    if (wv == 0) {
        float* dst = P + (size_t)ns * BB * CD;
#pragma unroll
        for (int c = 0; c < 10; ++c)
#pragma unroll
            for (int e = 0; e < 4; ++e)
                dst[(size_t)(btile + lo) * CD + c * 16 + g * 4 + e] =
                    acc[c][e] + red1[c * 256 + (g * 4 + e) * 16 + lo];
    }
}

extern "C" void kernel_launch(void* const* d_in, const int* in_sizes, int n_in,
                              void* d_out, int out_size, void* d_ws, size_t ws_size,
                              hipStream_t stream)
{
    (void)in_sizes; (void)n_in; (void)out_size;
    const float* x = (const float*)d_in[0];
    const float* w = (const float*)d_in[1];
    float* out = (float*)d_out;

    char* base = (char*)d_ws;
    short* wnh = (short*)(base);
    short* wnl = (short*)(base + 2949120);
    float* o0  = (float*)(base + 5898240);
    float* P   = (float*)(base + 6225920);
    const size_t fixed = 6225920, slab = (size_t)BB * CD * sizeof(float);

    p0<<<WELEM / 256, 256, 0, stream>>>(w, wnh, wnl);

#define LAUNCH_NS(NS1, NS2)                                                            \
    do {                                                                               \
        caps_p1<NS1><<<dim3(NS1, 32), 256, 0, stream>>>(x, wnh, wnl, P);               \
        reduce_squash<<<320, 256, 0, stream>>>(P, o0, NS1, 0.01f);                     \
        caps_p2<NS2><<<dim3(NS2, 32), 256, 0, stream>>>(x, wnh, wnl, o0, P);           \
        reduce_squash<<<320, 256, 0, stream>>>(P, out, NS2, 1.0f);                     \
    } while (0)

    if      (ws_size >= fixed + slab * 24) LAUNCH_NS(24, 16);   // p1: 768 blk == 3/CU slots;
    else if (ws_size >= fixed + slab * 12) LAUNCH_NS(12, 12);   // p2: 512 blk == 2/CU slots
    else                                   LAUNCH_NS(4, 4);
#undef LAUNCH_NS
}